// Round 1
// baseline (186.422 us; speedup 1.0000x reference)
//
#include <hip/hip_runtime.h>
#include <hip/hip_bf16.h>

#define NB 8192        // batch rows
#define M1T 139264     // NB * 17 rows in layer-1
#define FD 256         // feature dim
#define KD 512         // concat dim

typedef __attribute__((ext_vector_type(8))) short bf16x8;
typedef __attribute__((ext_vector_type(16))) float f32x16;

__device__ __forceinline__ unsigned short f2b(float f) {
  union { float f; unsigned u; } v; v.f = f;
  unsigned r = v.u + 0x7fffu + ((v.u >> 16) & 1u);   // RNE
  return (unsigned short)(r >> 16);
}
__device__ __forceinline__ float b2f(unsigned u16) {
  union { unsigned u; float f; } v; v.u = u16 << 16;
  return v.f;
}

// ---- kernel 0: W1/W2 fp32 -> bf16 (each 256x512 = 131072 elems) ----
__global__ void convert_w(const float* __restrict__ W1, const float* __restrict__ W2,
                          unsigned short* __restrict__ W1b, unsigned short* __restrict__ W2b) {
  int i = blockIdx.x * 256 + threadIdx.x;  // 0..65535, 4 elems each
  const float4* src;
  unsigned short* dst;
  if (i < 32768) { src = (const float4*)W1 + i; dst = W1b + (size_t)i * 4; }
  else           { src = (const float4*)W2 + (i - 32768); dst = W2b + (size_t)(i - 32768) * 4; }
  float4 v = *src;
  ushort4 o;
  o.x = f2b(v.x); o.y = f2b(v.y); o.z = f2b(v.z); o.w = f2b(v.w);
  *(ushort4*)dst = o;
}

// ---- layer 1: h1 = relu([self || mean4(neigh2)] @ W1^T), stored bf16 ----
// BM=64 rows/block, BN=256 (full), BK=64, 256 threads = 4 waves.
// Wave w owns cols [w*64, w*64+64): 2 M-tiles x 2 N-tiles of 32x32 MFMA.
__global__ __launch_bounds__(256, 2)
void sage_l1(const float* __restrict__ feats,
             const unsigned short* __restrict__ Wb,
             const int* __restrict__ batch_nodes,
             const int* __restrict__ neigh1,
             const int* __restrict__ neigh2,
             unsigned short* __restrict__ h1b)
{
  __shared__ __align__(16) unsigned short Asm[64 * 64];    // 8 KB  (swizzled)
  __shared__ __align__(16) unsigned short Bsm[256 * 64];   // 32 KB (swizzled)
  const int tid = threadIdx.x;
  const int m0 = blockIdx.x * 64;
  const int w = tid >> 6;
  const int l31 = tid & 31;
  const int lh = (tid & 63) >> 5;

  f32x16 acc[2][2] = {};

  for (int kt = 0; kt < 8; ++kt) {
    // ---- stage B: W tile, 256 rows(n) x 64 k, bf16 copy with slot swizzle
    #pragma unroll
    for (int p = 0; p < 8; ++p) {
      int s = p * 256 + tid;            // 0..2047 slots of 8 bf16
      int n = s >> 3, slot = s & 7;
      uint4 v = *(const uint4*)(Wb + (size_t)n * 512 + kt * 64 + slot * 8);
      *(uint4*)(Bsm + n * 64 + ((slot ^ (n & 7)) << 3)) = v;
    }
    // ---- stage A: 64 rows x 64 k, gathered fp32 -> bf16
    #pragma unroll
    for (int p = 0; p < 2; ++p) {
      int s = p * 256 + tid;            // 0..511 slots
      int m = s >> 3, slot = s & 7;
      int r = m0 + m;
      float f0, f1, f2, f3, f4, f5, f6, f7;
      if (kt < 4) {                     // self half (k = 0..255)
        int node = (r < NB) ? batch_nodes[r] : neigh1[r - NB];
        const float4* src = (const float4*)(feats + (size_t)node * 256 + kt * 64 + slot * 8);
        float4 x = src[0], y = src[1];
        f0 = x.x; f1 = x.y; f2 = x.z; f3 = x.w;
        f4 = y.x; f5 = y.y; f6 = y.z; f7 = y.w;
      } else {                          // agg half: mean of 4 neighbor rows
        int kb = (kt - 4) * 64 + slot * 8;
        float s0 = 0, s1 = 0, s2 = 0, s3 = 0, s4 = 0, s5 = 0, s6 = 0, s7 = 0;
        #pragma unroll
        for (int j = 0; j < 4; ++j) {
          int node = neigh2[(size_t)r * 4 + j];
          const float4* src = (const float4*)(feats + (size_t)node * 256 + kb);
          float4 x = src[0], y = src[1];
          s0 += x.x; s1 += x.y; s2 += x.z; s3 += x.w;
          s4 += y.x; s5 += y.y; s6 += y.z; s7 += y.w;
        }
        f0 = s0 * 0.25f; f1 = s1 * 0.25f; f2 = s2 * 0.25f; f3 = s3 * 0.25f;
        f4 = s4 * 0.25f; f5 = s5 * 0.25f; f6 = s6 * 0.25f; f7 = s7 * 0.25f;
      }
      uint4 v;
      v.x = (unsigned)f2b(f0) | ((unsigned)f2b(f1) << 16);
      v.y = (unsigned)f2b(f2) | ((unsigned)f2b(f3) << 16);
      v.z = (unsigned)f2b(f4) | ((unsigned)f2b(f5) << 16);
      v.w = (unsigned)f2b(f6) | ((unsigned)f2b(f7) << 16);
      *(uint4*)(Asm + m * 64 + ((slot ^ (m & 7)) << 3)) = v;
    }
    __syncthreads();
    // ---- compute: 4 k-steps of 16, 4 MFMA each
    #pragma unroll
    for (int kk = 0; kk < 4; ++kk) {
      int sl = kk * 2 + lh;
      bf16x8 a0, a1, b0, b1;
      { int row = l31;           a0 = *(const bf16x8*)(Asm + row * 64 + ((sl ^ (row & 7)) << 3)); }
      { int row = 32 + l31;      a1 = *(const bf16x8*)(Asm + row * 64 + ((sl ^ (row & 7)) << 3)); }
      { int n = w * 64 + l31;    b0 = *(const bf16x8*)(Bsm + n * 64 + ((sl ^ (n & 7)) << 3)); }
      { int n = w * 64 + 32 + l31; b1 = *(const bf16x8*)(Bsm + n * 64 + ((sl ^ (n & 7)) << 3)); }
      acc[0][0] = __builtin_amdgcn_mfma_f32_32x32x16_bf16(a0, b0, acc[0][0], 0, 0, 0);
      acc[0][1] = __builtin_amdgcn_mfma_f32_32x32x16_bf16(a0, b1, acc[0][1], 0, 0, 0);
      acc[1][0] = __builtin_amdgcn_mfma_f32_32x32x16_bf16(a1, b0, acc[1][0], 0, 0, 0);
      acc[1][1] = __builtin_amdgcn_mfma_f32_32x32x16_bf16(a1, b1, acc[1][1], 0, 0, 0);
    }
    __syncthreads();
  }
  // ---- epilogue: relu -> bf16 h1
  #pragma unroll
  for (int mi = 0; mi < 2; ++mi)
    #pragma unroll
    for (int ni = 0; ni < 2; ++ni)
      #pragma unroll
      for (int q = 0; q < 16; ++q) {
        int row = m0 + mi * 32 + (q & 3) + 8 * (q >> 2) + 4 * lh;
        int col = w * 64 + ni * 32 + l31;
        float v = acc[mi][ni][q];
        v = v > 0.f ? v : 0.f;
        h1b[(size_t)row * 256 + col] = f2b(v);
      }
}

// ---- layer 2: out = relu([h1_self || mean16(h1_neigh)] @ W2^T), fp32 out ----
__global__ __launch_bounds__(256, 2)
void sage_l2(const unsigned short* __restrict__ h1b,
             const unsigned short* __restrict__ Wb,
             float* __restrict__ out)
{
  __shared__ __align__(16) unsigned short Asm[64 * 64];
  __shared__ __align__(16) unsigned short Bsm[256 * 64];
  const int tid = threadIdx.x;
  const int m0 = blockIdx.x * 64;
  const int w = tid >> 6;
  const int l31 = tid & 31;
  const int lh = (tid & 63) >> 5;

  f32x16 acc[2][2] = {};

  for (int kt = 0; kt < 8; ++kt) {
    #pragma unroll
    for (int p = 0; p < 8; ++p) {
      int s = p * 256 + tid;
      int n = s >> 3, slot = s & 7;
      uint4 v = *(const uint4*)(Wb + (size_t)n * 512 + kt * 64 + slot * 8);
      *(uint4*)(Bsm + n * 64 + ((slot ^ (n & 7)) << 3)) = v;
    }
    #pragma unroll
    for (int p = 0; p < 2; ++p) {
      int s = p * 256 + tid;
      int m = s >> 3, slot = s & 7;
      int r = m0 + m;
      uint4 v;
      if (kt < 4) {                     // self half: h1 row r, direct bf16 copy
        v = *(const uint4*)(h1b + (size_t)r * 256 + kt * 64 + slot * 8);
      } else {                          // agg half: mean of 16 h1 rows
        int kb = (kt - 4) * 64 + slot * 8;
        float s0 = 0, s1 = 0, s2 = 0, s3 = 0, s4 = 0, s5 = 0, s6 = 0, s7 = 0;
        #pragma unroll
        for (int j = 0; j < 16; ++j) {
          uint4 t = *(const uint4*)(h1b + (size_t)(NB + r * 16 + j) * 256 + kb);
          s0 += b2f(t.x & 0xffffu); s1 += b2f(t.x >> 16);
          s2 += b2f(t.y & 0xffffu); s3 += b2f(t.y >> 16);
          s4 += b2f(t.z & 0xffffu); s5 += b2f(t.z >> 16);
          s6 += b2f(t.w & 0xffffu); s7 += b2f(t.w >> 16);
        }
        const float q = 1.0f / 16.0f;
        v.x = (unsigned)f2b(s0 * q) | ((unsigned)f2b(s1 * q) << 16);
        v.y = (unsigned)f2b(s2 * q) | ((unsigned)f2b(s3 * q) << 16);
        v.z = (unsigned)f2b(s4 * q) | ((unsigned)f2b(s5 * q) << 16);
        v.w = (unsigned)f2b(s6 * q) | ((unsigned)f2b(s7 * q) << 16);
      }
      *(uint4*)(Asm + m * 64 + ((slot ^ (m & 7)) << 3)) = v;
    }
    __syncthreads();
    #pragma unroll
    for (int kk = 0; kk < 4; ++kk) {
      int sl = kk * 2 + lh;
      bf16x8 a0, a1, b0, b1;
      { int row = l31;           a0 = *(const bf16x8*)(Asm + row * 64 + ((sl ^ (row & 7)) << 3)); }
      { int row = 32 + l31;      a1 = *(const bf16x8*)(Asm + row * 64 + ((sl ^ (row & 7)) << 3)); }
      { int n = w * 64 + l31;    b0 = *(const bf16x8*)(Bsm + n * 64 + ((sl ^ (n & 7)) << 3)); }
      { int n = w * 64 + 32 + l31; b1 = *(const bf16x8*)(Bsm + n * 64 + ((sl ^ (n & 7)) << 3)); }
      acc[0][0] = __builtin_amdgcn_mfma_f32_32x32x16_bf16(a0, b0, acc[0][0], 0, 0, 0);
      acc[0][1] = __builtin_amdgcn_mfma_f32_32x32x16_bf16(a0, b1, acc[0][1], 0, 0, 0);
      acc[1][0] = __builtin_amdgcn_mfma_f32_32x32x16_bf16(a1, b0, acc[1][0], 0, 0, 0);
      acc[1][1] = __builtin_amdgcn_mfma_f32_32x32x16_bf16(a1, b1, acc[1][1], 0, 0, 0);
    }
    __syncthreads();
  }
  #pragma unroll
  for (int mi = 0; mi < 2; ++mi)
    #pragma unroll
    for (int ni = 0; ni < 2; ++ni)
      #pragma unroll
      for (int q = 0; q < 16; ++q) {
        int row = m0 + mi * 32 + (q & 3) + 8 * (q >> 2) + 4 * lh;
        int col = w * 64 + ni * 32 + l31;
        float v = acc[mi][ni][q];
        out[(size_t)row * 256 + col] = v > 0.f ? v : 0.f;
      }
}

extern "C" void kernel_launch(void* const* d_in, const int* in_sizes, int n_in,
                              void* d_out, int out_size, void* d_ws, size_t ws_size,
                              hipStream_t stream) {
  const float* feats       = (const float*)d_in[0];
  const float* W1          = (const float*)d_in[1];
  const float* W2          = (const float*)d_in[2];
  const int*   batch_nodes = (const int*)d_in[3];
  const int*   neigh1      = (const int*)d_in[4];
  const int*   neigh2      = (const int*)d_in[5];
  float* out = (float*)d_out;

  unsigned short* W1b = (unsigned short*)d_ws;            // 131072 elems
  unsigned short* W2b = W1b + 131072;                     // 131072 elems
  unsigned short* h1b = W2b + 131072;                     // 139264*256 elems (~71 MB)

  hipLaunchKernelGGL(convert_w, dim3(256), dim3(256), 0, stream, W1, W2, W1b, W2b);
  hipLaunchKernelGGL(sage_l1, dim3(M1T / 64), dim3(256), 0, stream,
                     feats, W1b, batch_nodes, neigh1, neigh2, h1b);
  hipLaunchKernelGGL(sage_l2, dim3(NB / 64), dim3(256), 0, stream, h1b, W2b, out);
}